// Round 13
// baseline (288.215 us; speedup 1.0000x reference)
//
#include <hip/hip_runtime.h>
#include <math.h>

#define H_N 1024
#define M_N 8
#define HM 8192
#define NIC 64   // i-chunks for split-K gemv

typedef float f32x4 __attribute__((ext_vector_type(4)));

static __device__ __forceinline__ float log_eps(float x) {
    const float EPS_TINY = 1.17549435e-38f;
    return __logf(x <= 0.0f ? EPS_TINY : x);
}

// ---------------- kernel 1: pbuf[ic][j] = sum_{i in chunk ic} w[i][j] * o[i] -------
// EXACT R6/R11 version. No atomics, coalesced dwordx4 out.
__global__ __launch_bounds__(256) void gemv_partial(const float* __restrict__ w,
                                                    const float* __restrict__ o,
                                                    float* __restrict__ pbuf) {
    const int jb = blockIdx.x & 7;   // 8 j-blocks of 1024 columns
    const int ic = blockIdx.x >> 3;  // 64 i-chunks of 128 rows
    const int j0 = jb * 1024 + threadIdx.x * 4;
    const int i0 = ic * 128;
    f32x4 acc = {0.f, 0.f, 0.f, 0.f};
    const float* wp = w + (size_t)i0 * HM + j0;
#pragma unroll 4
    for (int i = 0; i < 128; ++i) {
        const float ov = o[i0 + i];
        const f32x4 wv = *reinterpret_cast<const f32x4*>(wp);
        acc.x += wv.x * ov; acc.y += wv.y * ov; acc.z += wv.z * ov; acc.w += wv.w * ov;
        wp += HM;
    }
    *reinterpret_cast<f32x4*>(&pbuf[(size_t)ic * HM + j0]) = acc;
}

// ---------------- kernel 2: reduce partials + per-row state update (EXACT R6) ------
__global__ __launch_bounds__(256) void row_kernel(
    const float* __restrict__ x, const float* __restrict__ s,
    const float* __restrict__ a, const float* __restrict__ zi,
    const float* __restrict__ zj, const float* __restrict__ p,
    const float* __restrict__ pi, const float* __restrict__ pj,
    const float* __restrict__ b, const float* __restrict__ noise,
    const float* __restrict__ ga, const float* __restrict__ gw,
    const float* __restrict__ gb, const float* __restrict__ gs,
    const float* __restrict__ k, const float* __restrict__ pbuf,
    float* __restrict__ out) {
    const int r = blockIdx.x * blockDim.x + threadIdx.x;
    if (r >= H_N) return;

    const float gwv = gw[0], gav = ga[0], gbv = gb[0], gsv = gs[0], kv = k[0], pv = p[0];
    const float c = kv * 1e-4f;   // k*DT/TP

    float* o_new  = out;
    float* s_new  = out + (size_t)HM;
    float* a_new  = out + (size_t)2 * HM;
    float* zi_new = out + (size_t)3 * HM;
    float* zj_new = out + (size_t)4 * HM;
    float* p_new  = out + (size_t)5 * HM;          // 1 element
    float* pi_new = out + (size_t)5 * HM + 1;
    float* pj_new = out + (size_t)6 * HM + 1;
    float* b_new  = out + (size_t)7 * HM + 1 + (size_t)2 * HM * HM;

    const int base = r * M_N;

    f32x4 r0 = {0.f, 0.f, 0.f, 0.f}, r1 = {0.f, 0.f, 0.f, 0.f};
#pragma unroll 8
    for (int ic = 0; ic < NIC; ++ic) {
        const float* pp = pbuf + (size_t)ic * HM + base;
        const f32x4 v0 = *reinterpret_cast<const f32x4*>(pp);
        const f32x4 v1 = *reinterpret_cast<const f32x4*>(pp + 4);
        r0.x += v0.x; r0.y += v0.y; r0.z += v0.z; r0.w += v0.w;
        r1.x += v1.x; r1.y += v1.y; r1.z += v1.z; r1.w += v1.w;
    }
    const float stv[M_N] = {r0.x, r0.y, r0.z, r0.w, r1.x, r1.y, r1.z, r1.w};

    float sv[M_N], ev[M_N];
    float mx = -3.0e38f;
#pragma unroll
    for (int m = 0; m < M_N; ++m) {
        const int i = base + m;
        const float st = gwv * (b[i] + stv[m]);
        const float sn = s[i] + 0.02f * (st - a[i] + log_eps(x[i]) + gsv * noise[i] - s[i]);
        sv[m] = sn;
        mx = fmaxf(mx, sn);
    }
    float sum = 0.f;
#pragma unroll
    for (int m = 0; m < M_N; ++m) { ev[m] = __expf(sv[m] - mx); sum += ev[m]; }
    const float rs = 1.0f / sum;
#pragma unroll
    for (int m = 0; m < M_N; ++m) {
        const int i = base + m;
        const float on  = ev[m] * rs;
        const float an  = a[i]  + (float)(0.001 / 2.7)  * (gav * on - a[i]);
        const float zin = zi[i] + (float)(0.001 / 0.24) * (on - zi[i]);
        const float zjn = zj[i] + (float)(0.001 / 0.24) * (on - zj[i]);
        const float pin = pi[i] + c * (zin - pi[i]);
        const float pjn = pj[i] + c * (zjn - pj[i]);
        o_new[i]  = on;
        s_new[i]  = sv[m];
        a_new[i]  = an;
        zi_new[i] = zin;
        zj_new[i] = zjn;
        pi_new[i] = pin;
        pj_new[i] = pjn;
        b_new[i]  = gbv * log_eps(pjn);
    }
    if (r == 0) p_new[0] = pv + c * (1.0f - pv);
}

// ---------------- kernel 3: pij_new + w_new — TRANSPOSED thread mapping ------------
// Thread = one column j, 4 consecutive rows. Every load/store instruction is
// lane-stride-4B dense (256B runs): no redundant line touches, no straddle,
// no shuffles. zi/pi indices are wave-uniform (broadcast).
// Tiles: stripe s in [0,2048) x colblock cb in [0,32); 65536 tiles, grid-stride.
__global__ __launch_bounds__(256) void outer_kernel(
    const float* __restrict__ pij, const float* __restrict__ out_ro,
    float* __restrict__ out, const float* __restrict__ p,
    const float* __restrict__ k) {
    const float* zi_new = out_ro + (size_t)3 * HM;
    const float* zj_new = out_ro + (size_t)4 * HM;
    const float* pi_new = out_ro + (size_t)5 * HM + 1;
    const float* pj_new = out_ro + (size_t)6 * HM + 1;
    float* pij_new = out + (size_t)7 * HM + 1;
    float* w_new   = pij_new + (size_t)HM * HM;

    const float kv = k[0], pv = p[0];
    const float c  = kv * 1e-4f;
    const float pn = pv + c * (1.0f - pv);

    const int ntiles = 2048 * 32;           // stripes x colblocks
    for (int tau = blockIdx.x; tau < ntiles; tau += gridDim.x) {
        const int stripe = tau >> 5;        // 4-row stripe
        const int cb     = tau & 31;        // 256-column block
        const int j  = cb * 256 + threadIdx.x;
        const int I0 = stripe * 4;

        const float zjv = zj_new[j];
        const float pjv = pj_new[j];

#pragma unroll
        for (int m = 0; m < 4; ++m) {
            const int I = I0 + m;
            const float ziI = zi_new[I];    // wave-uniform
            const float piI = pi_new[I];    // wave-uniform
            const size_t e = (size_t)I * HM + j;
            const float pe = pij[e];
            const float q  = pe + c * (ziI * zjv - pe);
            pij_new[e] = q;
            w_new[e]   = log_eps(__fdividef(pn * q, piI * pjv));
        }
    }
}

extern "C" void kernel_launch(void* const* d_in, const int* in_sizes, int n_in,
                              void* d_out, int out_size, void* d_ws, size_t ws_size,
                              hipStream_t stream) {
    const float* x     = (const float*)d_in[0];
    const float* s     = (const float*)d_in[1];
    const float* o     = (const float*)d_in[2];
    const float* a     = (const float*)d_in[3];
    const float* zi    = (const float*)d_in[4];
    const float* zj    = (const float*)d_in[5];
    const float* p     = (const float*)d_in[6];
    const float* pi    = (const float*)d_in[7];
    const float* pj    = (const float*)d_in[8];
    const float* pij   = (const float*)d_in[9];
    const float* b     = (const float*)d_in[10];
    const float* w     = (const float*)d_in[11];
    const float* noise = (const float*)d_in[12];
    const float* ga    = (const float*)d_in[13];
    const float* gw    = (const float*)d_in[14];
    const float* gb    = (const float*)d_in[15];
    const float* gs    = (const float*)d_in[16];
    const float* k     = (const float*)d_in[17];

    float* out  = (float*)d_out;
    float* pbuf = (float*)d_ws;          // NIC * HM floats = 2 MB of scratch

    gemv_partial<<<512, 256, 0, stream>>>(w, o, pbuf);
    row_kernel<<<(H_N + 255) / 256, 256, 0, stream>>>(
        x, s, a, zi, zj, p, pi, pj, b, noise, ga, gw, gb, gs, k, pbuf, out);
    outer_kernel<<<2048, 256, 0, stream>>>(pij, out, out, p, k);
}

// Round 14
// 254.922 us; speedup vs baseline: 1.1306x; 1.1306x over previous
//
#include <hip/hip_runtime.h>
#include <math.h>

#define H_N 1024
#define M_N 8
#define HM 8192
#define NIC 64   // i-chunks for split-K gemv

typedef float f32x4 __attribute__((ext_vector_type(4)));
typedef float f32x4u __attribute__((ext_vector_type(4), aligned(4)));

static __device__ __forceinline__ float log_eps(float x) {
    const float EPS_TINY = 1.17549435e-38f;
    return __logf(x <= 0.0f ? EPS_TINY : x);
}

// ---------------- kernel 1: pbuf[ic][j] = sum_{i in chunk ic} w[i][j] * o[i] -------
// EXACT R6/R11 version. No atomics, coalesced dwordx4 out.
__global__ __launch_bounds__(256) void gemv_partial(const float* __restrict__ w,
                                                    const float* __restrict__ o,
                                                    float* __restrict__ pbuf) {
    const int jb = blockIdx.x & 7;   // 8 j-blocks of 1024 columns
    const int ic = blockIdx.x >> 3;  // 64 i-chunks of 128 rows
    const int j0 = jb * 1024 + threadIdx.x * 4;
    const int i0 = ic * 128;
    f32x4 acc = {0.f, 0.f, 0.f, 0.f};
    const float* wp = w + (size_t)i0 * HM + j0;
#pragma unroll 4
    for (int i = 0; i < 128; ++i) {
        const float ov = o[i0 + i];
        const f32x4 wv = *reinterpret_cast<const f32x4*>(wp);
        acc.x += wv.x * ov; acc.y += wv.y * ov; acc.z += wv.z * ov; acc.w += wv.w * ov;
        wp += HM;
    }
    *reinterpret_cast<f32x4*>(&pbuf[(size_t)ic * HM + j0]) = acc;
}

// ---------------- kernel 2: reduce partials + per-row state update (EXACT R6) ------
__global__ __launch_bounds__(256) void row_kernel(
    const float* __restrict__ x, const float* __restrict__ s,
    const float* __restrict__ a, const float* __restrict__ zi,
    const float* __restrict__ zj, const float* __restrict__ p,
    const float* __restrict__ pi, const float* __restrict__ pj,
    const float* __restrict__ b, const float* __restrict__ noise,
    const float* __restrict__ ga, const float* __restrict__ gw,
    const float* __restrict__ gb, const float* __restrict__ gs,
    const float* __restrict__ k, const float* __restrict__ pbuf,
    float* __restrict__ out) {
    const int r = blockIdx.x * blockDim.x + threadIdx.x;
    if (r >= H_N) return;

    const float gwv = gw[0], gav = ga[0], gbv = gb[0], gsv = gs[0], kv = k[0], pv = p[0];
    const float c = kv * 1e-4f;   // k*DT/TP

    float* o_new  = out;
    float* s_new  = out + (size_t)HM;
    float* a_new  = out + (size_t)2 * HM;
    float* zi_new = out + (size_t)3 * HM;
    float* zj_new = out + (size_t)4 * HM;
    float* p_new  = out + (size_t)5 * HM;          // 1 element
    float* pi_new = out + (size_t)5 * HM + 1;
    float* pj_new = out + (size_t)6 * HM + 1;
    float* b_new  = out + (size_t)7 * HM + 1 + (size_t)2 * HM * HM;

    const int base = r * M_N;

    f32x4 r0 = {0.f, 0.f, 0.f, 0.f}, r1 = {0.f, 0.f, 0.f, 0.f};
#pragma unroll 8
    for (int ic = 0; ic < NIC; ++ic) {
        const float* pp = pbuf + (size_t)ic * HM + base;
        const f32x4 v0 = *reinterpret_cast<const f32x4*>(pp);
        const f32x4 v1 = *reinterpret_cast<const f32x4*>(pp + 4);
        r0.x += v0.x; r0.y += v0.y; r0.z += v0.z; r0.w += v0.w;
        r1.x += v1.x; r1.y += v1.y; r1.z += v1.z; r1.w += v1.w;
    }
    const float stv[M_N] = {r0.x, r0.y, r0.z, r0.w, r1.x, r1.y, r1.z, r1.w};

    float sv[M_N], ev[M_N];
    float mx = -3.0e38f;
#pragma unroll
    for (int m = 0; m < M_N; ++m) {
        const int i = base + m;
        const float st = gwv * (b[i] + stv[m]);
        const float sn = s[i] + 0.02f * (st - a[i] + log_eps(x[i]) + gsv * noise[i] - s[i]);
        sv[m] = sn;
        mx = fmaxf(mx, sn);
    }
    float sum = 0.f;
#pragma unroll
    for (int m = 0; m < M_N; ++m) { ev[m] = __expf(sv[m] - mx); sum += ev[m]; }
    const float rs = 1.0f / sum;
#pragma unroll
    for (int m = 0; m < M_N; ++m) {
        const int i = base + m;
        const float on  = ev[m] * rs;
        const float an  = a[i]  + (float)(0.001 / 2.7)  * (gav * on - a[i]);
        const float zin = zi[i] + (float)(0.001 / 0.24) * (on - zi[i]);
        const float zjn = zj[i] + (float)(0.001 / 0.24) * (on - zj[i]);
        const float pin = pi[i] + c * (zin - pi[i]);
        const float pjn = pj[i] + c * (zjn - pj[i]);
        o_new[i]  = on;
        s_new[i]  = sv[m];
        a_new[i]  = an;
        zi_new[i] = zin;
        zj_new[i] = zjn;
        pi_new[i] = pin;
        pj_new[i] = pjn;
        b_new[i]  = gbv * log_eps(pjn);
    }
    if (r == 0) p_new[0] = pv + c * (1.0f - pv);
}

// ---------------- kernel 3: pij_new + w_new — R11 body, 2-deep read pipeline -------
// Single change vs R11: each iteration handles quads v and v+S (S = total threads),
// with ALL loads issued before compute/stores. 4S ≡ 0 mod HM -> same J, so the
// zj/pj vector gathers are shared; only pij loads and zi/pi broadcasts double.
// nvec = 32*S exactly -> pair loop needs no bounds checks.
__global__ __launch_bounds__(256) void outer_kernel(
    const float* __restrict__ pij, const float* __restrict__ out_ro,
    float* __restrict__ out, const float* __restrict__ p,
    const float* __restrict__ k) {
    const float* zi_new = out_ro + (size_t)3 * HM;
    const float* zj_new = out_ro + (size_t)4 * HM;
    const float* pi_new = out_ro + (size_t)5 * HM + 1;
    const float* pj_new = out_ro + (size_t)6 * HM + 1;
    float* pij_new = out + (size_t)7 * HM + 1;
    float* w_new   = pij_new + (size_t)HM * HM;

    const float kv = k[0], pv = p[0];
    const float c  = kv * 1e-4f;
    const float pn = pv + c * (1.0f - pv);

    const size_t nvec = (size_t)HM * HM / 4;
    const size_t S    = (size_t)gridDim.x * blockDim.x;   // 524288 when grid=2048x256
    for (size_t v = (size_t)blockIdx.x * blockDim.x + threadIdx.x; v + S < nvec + 1; v += 2 * S) {
        const size_t idxA = v * 4;
        const size_t idxB = (v + S) * 4;
        const int IA = (int)(idxA >> 13);
        const int IB = (int)(idxB >> 13);
        const int J  = (int)(idxA & 8191);   // identical for B when 4S % 8192 == 0

        // ---- all loads issued up front ----
        const f32x4 pvA = *reinterpret_cast<const f32x4*>(&pij[idxA]);
        const f32x4 pvB = *reinterpret_cast<const f32x4*>(&pij[idxB]);
        const f32x4  zj4 = *reinterpret_cast<const f32x4*>(&zj_new[J]);    // 16B aligned
        const f32x4u pj4 = *reinterpret_cast<const f32x4u*>(&pj_new[J]);   // 4B aligned
        const float ziA = zi_new[IA], piA = pi_new[IA];
        const float ziB = zi_new[IB], piB = pi_new[IB];

        // ---- quad A ----
        {
            const float q0 = pvA.x + c * (ziA * zj4.x - pvA.x);
            const float q1 = pvA.y + c * (ziA * zj4.y - pvA.y);
            const float q2 = pvA.z + c * (ziA * zj4.z - pvA.z);
            const float q3 = pvA.w + c * (ziA * zj4.w - pvA.w);
            pij_new[idxA + 0] = q0;
            pij_new[idxA + 1] = q1;
            pij_new[idxA + 2] = q2;
            pij_new[idxA + 3] = q3;
            w_new[idxA + 0] = log_eps(__fdividef(pn * q0, piA * pj4.x));
            w_new[idxA + 1] = log_eps(__fdividef(pn * q1, piA * pj4.y));
            w_new[idxA + 2] = log_eps(__fdividef(pn * q2, piA * pj4.z));
            w_new[idxA + 3] = log_eps(__fdividef(pn * q3, piA * pj4.w));
        }
        // ---- quad B ----
        {
            const float q0 = pvB.x + c * (ziB * zj4.x - pvB.x);
            const float q1 = pvB.y + c * (ziB * zj4.y - pvB.y);
            const float q2 = pvB.z + c * (ziB * zj4.z - pvB.z);
            const float q3 = pvB.w + c * (ziB * zj4.w - pvB.w);
            pij_new[idxB + 0] = q0;
            pij_new[idxB + 1] = q1;
            pij_new[idxB + 2] = q2;
            pij_new[idxB + 3] = q3;
            w_new[idxB + 0] = log_eps(__fdividef(pn * q0, piB * pj4.x));
            w_new[idxB + 1] = log_eps(__fdividef(pn * q1, piB * pj4.y));
            w_new[idxB + 2] = log_eps(__fdividef(pn * q2, piB * pj4.z));
            w_new[idxB + 3] = log_eps(__fdividef(pn * q3, piB * pj4.w));
        }
    }
}

extern "C" void kernel_launch(void* const* d_in, const int* in_sizes, int n_in,
                              void* d_out, int out_size, void* d_ws, size_t ws_size,
                              hipStream_t stream) {
    const float* x     = (const float*)d_in[0];
    const float* s     = (const float*)d_in[1];
    const float* o     = (const float*)d_in[2];
    const float* a     = (const float*)d_in[3];
    const float* zi    = (const float*)d_in[4];
    const float* zj    = (const float*)d_in[5];
    const float* p     = (const float*)d_in[6];
    const float* pi    = (const float*)d_in[7];
    const float* pj    = (const float*)d_in[8];
    const float* pij   = (const float*)d_in[9];
    const float* b     = (const float*)d_in[10];
    const float* w     = (const float*)d_in[11];
    const float* noise = (const float*)d_in[12];
    const float* ga    = (const float*)d_in[13];
    const float* gw    = (const float*)d_in[14];
    const float* gb    = (const float*)d_in[15];
    const float* gs    = (const float*)d_in[16];
    const float* k     = (const float*)d_in[17];

    float* out  = (float*)d_out;
    float* pbuf = (float*)d_ws;          // NIC * HM floats = 2 MB of scratch

    gemv_partial<<<512, 256, 0, stream>>>(w, o, pbuf);
    row_kernel<<<(H_N + 255) / 256, 256, 0, stream>>>(
        x, s, a, zi, zj, p, pi, pj, b, noise, ga, gw, gb, gs, k, pbuf, out);
    outer_kernel<<<2048, 256, 0, stream>>>(pij, out, out, p, k);
}

// Round 15
// 254.914 us; speedup vs baseline: 1.1306x; 1.0000x over previous
//
#include <hip/hip_runtime.h>
#include <math.h>

#define H_N 1024
#define M_N 8
#define HM 8192
#define NIC 64   // i-chunks for split-K gemv

typedef float f32x4 __attribute__((ext_vector_type(4)));
typedef float f32x4u __attribute__((ext_vector_type(4), aligned(4)));

static __device__ __forceinline__ float log_eps(float x) {
    const float EPS_TINY = 1.17549435e-38f;
    return __logf(x <= 0.0f ? EPS_TINY : x);
}

// ---------------- kernel 1: pbuf[ic][j] = sum_{i in chunk ic} w[i][j] * o[i] -------
// EXACT R6/R11 version. No atomics, coalesced dwordx4 out.
__global__ __launch_bounds__(256) void gemv_partial(const float* __restrict__ w,
                                                    const float* __restrict__ o,
                                                    float* __restrict__ pbuf) {
    const int jb = blockIdx.x & 7;   // 8 j-blocks of 1024 columns
    const int ic = blockIdx.x >> 3;  // 64 i-chunks of 128 rows
    const int j0 = jb * 1024 + threadIdx.x * 4;
    const int i0 = ic * 128;
    f32x4 acc = {0.f, 0.f, 0.f, 0.f};
    const float* wp = w + (size_t)i0 * HM + j0;
#pragma unroll 4
    for (int i = 0; i < 128; ++i) {
        const float ov = o[i0 + i];
        const f32x4 wv = *reinterpret_cast<const f32x4*>(wp);
        acc.x += wv.x * ov; acc.y += wv.y * ov; acc.z += wv.z * ov; acc.w += wv.w * ov;
        wp += HM;
    }
    *reinterpret_cast<f32x4*>(&pbuf[(size_t)ic * HM + j0]) = acc;
}

// ---------------- kernel 2: reduce partials + per-row state update (EXACT R6) ------
__global__ __launch_bounds__(256) void row_kernel(
    const float* __restrict__ x, const float* __restrict__ s,
    const float* __restrict__ a, const float* __restrict__ zi,
    const float* __restrict__ zj, const float* __restrict__ p,
    const float* __restrict__ pi, const float* __restrict__ pj,
    const float* __restrict__ b, const float* __restrict__ noise,
    const float* __restrict__ ga, const float* __restrict__ gw,
    const float* __restrict__ gb, const float* __restrict__ gs,
    const float* __restrict__ k, const float* __restrict__ pbuf,
    float* __restrict__ out) {
    const int r = blockIdx.x * blockDim.x + threadIdx.x;
    if (r >= H_N) return;

    const float gwv = gw[0], gav = ga[0], gbv = gb[0], gsv = gs[0], kv = k[0], pv = p[0];
    const float c = kv * 1e-4f;   // k*DT/TP

    float* o_new  = out;
    float* s_new  = out + (size_t)HM;
    float* a_new  = out + (size_t)2 * HM;
    float* zi_new = out + (size_t)3 * HM;
    float* zj_new = out + (size_t)4 * HM;
    float* p_new  = out + (size_t)5 * HM;          // 1 element
    float* pi_new = out + (size_t)5 * HM + 1;
    float* pj_new = out + (size_t)6 * HM + 1;
    float* b_new  = out + (size_t)7 * HM + 1 + (size_t)2 * HM * HM;

    const int base = r * M_N;

    f32x4 r0 = {0.f, 0.f, 0.f, 0.f}, r1 = {0.f, 0.f, 0.f, 0.f};
#pragma unroll 8
    for (int ic = 0; ic < NIC; ++ic) {
        const float* pp = pbuf + (size_t)ic * HM + base;
        const f32x4 v0 = *reinterpret_cast<const f32x4*>(pp);
        const f32x4 v1 = *reinterpret_cast<const f32x4*>(pp + 4);
        r0.x += v0.x; r0.y += v0.y; r0.z += v0.z; r0.w += v0.w;
        r1.x += v1.x; r1.y += v1.y; r1.z += v1.z; r1.w += v1.w;
    }
    const float stv[M_N] = {r0.x, r0.y, r0.z, r0.w, r1.x, r1.y, r1.z, r1.w};

    float sv[M_N], ev[M_N];
    float mx = -3.0e38f;
#pragma unroll
    for (int m = 0; m < M_N; ++m) {
        const int i = base + m;
        const float st = gwv * (b[i] + stv[m]);
        const float sn = s[i] + 0.02f * (st - a[i] + log_eps(x[i]) + gsv * noise[i] - s[i]);
        sv[m] = sn;
        mx = fmaxf(mx, sn);
    }
    float sum = 0.f;
#pragma unroll
    for (int m = 0; m < M_N; ++m) { ev[m] = __expf(sv[m] - mx); sum += ev[m]; }
    const float rs = 1.0f / sum;
#pragma unroll
    for (int m = 0; m < M_N; ++m) {
        const int i = base + m;
        const float on  = ev[m] * rs;
        const float an  = a[i]  + (float)(0.001 / 2.7)  * (gav * on - a[i]);
        const float zin = zi[i] + (float)(0.001 / 0.24) * (on - zi[i]);
        const float zjn = zj[i] + (float)(0.001 / 0.24) * (on - zj[i]);
        const float pin = pi[i] + c * (zin - pi[i]);
        const float pjn = pj[i] + c * (zjn - pj[i]);
        o_new[i]  = on;
        s_new[i]  = sv[m];
        a_new[i]  = an;
        zi_new[i] = zin;
        zj_new[i] = zjn;
        pi_new[i] = pin;
        pj_new[i] = pjn;
        b_new[i]  = gbv * log_eps(pjn);
    }
    if (r == 0) p_new[0] = pv + c * (1.0f - pv);
}

// ---------------- kernel 3: pij_new + w_new — R14 body, stores fused to dwordx4 ----
// Single change vs R14: each quad's 4 consecutive scalar stores become one
// 4B-aligned vector store (f32x4u). gfx950 supports dword-aligned dwordx4.
__global__ __launch_bounds__(256) void outer_kernel(
    const float* __restrict__ pij, const float* __restrict__ out_ro,
    float* __restrict__ out, const float* __restrict__ p,
    const float* __restrict__ k) {
    const float* zi_new = out_ro + (size_t)3 * HM;
    const float* zj_new = out_ro + (size_t)4 * HM;
    const float* pi_new = out_ro + (size_t)5 * HM + 1;
    const float* pj_new = out_ro + (size_t)6 * HM + 1;
    float* pij_new = out + (size_t)7 * HM + 1;
    float* w_new   = pij_new + (size_t)HM * HM;

    const float kv = k[0], pv = p[0];
    const float c  = kv * 1e-4f;
    const float pn = pv + c * (1.0f - pv);

    const size_t nvec = (size_t)HM * HM / 4;
    const size_t S    = (size_t)gridDim.x * blockDim.x;   // 524288 when grid=2048x256
    for (size_t v = (size_t)blockIdx.x * blockDim.x + threadIdx.x; v + S < nvec + 1; v += 2 * S) {
        const size_t idxA = v * 4;
        const size_t idxB = (v + S) * 4;
        const int IA = (int)(idxA >> 13);
        const int IB = (int)(idxB >> 13);
        const int J  = (int)(idxA & 8191);   // identical for B when 4S % 8192 == 0

        // ---- all loads issued up front ----
        const f32x4 pvA = *reinterpret_cast<const f32x4*>(&pij[idxA]);
        const f32x4 pvB = *reinterpret_cast<const f32x4*>(&pij[idxB]);
        const f32x4  zj4 = *reinterpret_cast<const f32x4*>(&zj_new[J]);    // 16B aligned
        const f32x4u pj4 = *reinterpret_cast<const f32x4u*>(&pj_new[J]);   // 4B aligned
        const float ziA = zi_new[IA], piA = pi_new[IA];
        const float ziB = zi_new[IB], piB = pi_new[IB];

        // ---- quad A ----
        {
            f32x4 Q, W;
            Q.x = pvA.x + c * (ziA * zj4.x - pvA.x);
            Q.y = pvA.y + c * (ziA * zj4.y - pvA.y);
            Q.z = pvA.z + c * (ziA * zj4.z - pvA.z);
            Q.w = pvA.w + c * (ziA * zj4.w - pvA.w);
            *reinterpret_cast<f32x4u*>(&pij_new[idxA]) = Q;
            W.x = log_eps(__fdividef(pn * Q.x, piA * pj4.x));
            W.y = log_eps(__fdividef(pn * Q.y, piA * pj4.y));
            W.z = log_eps(__fdividef(pn * Q.z, piA * pj4.z));
            W.w = log_eps(__fdividef(pn * Q.w, piA * pj4.w));
            *reinterpret_cast<f32x4u*>(&w_new[idxA]) = W;
        }
        // ---- quad B ----
        {
            f32x4 Q, W;
            Q.x = pvB.x + c * (ziB * zj4.x - pvB.x);
            Q.y = pvB.y + c * (ziB * zj4.y - pvB.y);
            Q.z = pvB.z + c * (ziB * zj4.z - pvB.z);
            Q.w = pvB.w + c * (ziB * zj4.w - pvB.w);
            *reinterpret_cast<f32x4u*>(&pij_new[idxB]) = Q;
            W.x = log_eps(__fdividef(pn * Q.x, piB * pj4.x));
            W.y = log_eps(__fdividef(pn * Q.y, piB * pj4.y));
            W.z = log_eps(__fdividef(pn * Q.z, piB * pj4.z));
            W.w = log_eps(__fdividef(pn * Q.w, piB * pj4.w));
            *reinterpret_cast<f32x4u*>(&w_new[idxB]) = W;
        }
    }
}

extern "C" void kernel_launch(void* const* d_in, const int* in_sizes, int n_in,
                              void* d_out, int out_size, void* d_ws, size_t ws_size,
                              hipStream_t stream) {
    const float* x     = (const float*)d_in[0];
    const float* s     = (const float*)d_in[1];
    const float* o     = (const float*)d_in[2];
    const float* a     = (const float*)d_in[3];
    const float* zi    = (const float*)d_in[4];
    const float* zj    = (const float*)d_in[5];
    const float* p     = (const float*)d_in[6];
    const float* pi    = (const float*)d_in[7];
    const float* pj    = (const float*)d_in[8];
    const float* pij   = (const float*)d_in[9];
    const float* b     = (const float*)d_in[10];
    const float* w     = (const float*)d_in[11];
    const float* noise = (const float*)d_in[12];
    const float* ga    = (const float*)d_in[13];
    const float* gw    = (const float*)d_in[14];
    const float* gb    = (const float*)d_in[15];
    const float* gs    = (const float*)d_in[16];
    const float* k     = (const float*)d_in[17];

    float* out  = (float*)d_out;
    float* pbuf = (float*)d_ws;          // NIC * HM floats = 2 MB of scratch

    gemv_partial<<<512, 256, 0, stream>>>(w, o, pbuf);
    row_kernel<<<(H_N + 255) / 256, 256, 0, stream>>>(
        x, s, a, zi, zj, p, pi, pj, b, noise, ga, gw, gb, gs, k, pbuf, out);
    outer_kernel<<<2048, 256, 0, stream>>>(pij, out, out, p, k);
}